// Round 3
// baseline (393.679 us; speedup 1.0000x reference)
//
#include <hip/hip_runtime.h>
#include <hip/hip_cooperative_groups.h>
#include <math.h>

namespace cg = cooperative_groups;

#define Bn   32
#define Cn   768
#define CRn  192
#define HWn  1024                 // H*W, contiguous innermost per (b,c)
#define ROWS (Bn * Cn)            // 24576 rows of 1024 floats
#define NBLK 1024
#define NWAVE (NBLK * 4)          // 4096 waves in grid

__device__ __forceinline__ float wave_sum_bcast(float v) {
    // butterfly: every lane ends with the full 64-lane sum
    #pragma unroll
    for (int off = 32; off > 0; off >>= 1) v += __shfl_xor(v, off);
    return v;
}

// Single cooperative kernel: squeeze -> (sync) -> MLP-h -> (sync) -> gate+scale.
// All reductions are wave-level (no LDS, no __syncthreads).
__global__ __launch_bounds__(256, 4) void se_fused(const float* __restrict__ x,
                                                   const float* __restrict__ w1,
                                                   const float* __restrict__ b1,
                                                   const float* __restrict__ w2,
                                                   const float* __restrict__ b2,
                                                   float* __restrict__ out,
                                                   float* __restrict__ s,   // [ROWS]
                                                   float* __restrict__ h) { // [Bn*CRn]
    cg::grid_group grid = cg::this_grid();
    const int lane = threadIdx.x & 63;
    const int w    = (blockIdx.x * blockDim.x + threadIdx.x) >> 6;  // global wave id

    // ---------- Phase 1: s[r] = mean(x[r, :]) ----------
    for (int r = w; r < ROWS; r += NWAVE) {
        const float4* xp = (const float4*)(x + (size_t)r * HWn);
        float sum = 0.0f;
        #pragma unroll
        for (int t = 0; t < 4; ++t) {
            float4 v = xp[lane + 64 * t];       // 1 KB contiguous per t, coalesced
            sum += v.x + v.y + v.z + v.w;
        }
        sum = wave_sum_bcast(sum);
        if (lane == 0) s[r] = sum * (1.0f / (float)HWn);
    }
    grid.sync();

    // ---------- Phase 2: h[b,j] = swish(s[b,:] . w1[j,:] + b1[j]) ----------
    for (int d = w; d < Bn * CRn; d += NWAVE) {
        const int b = d / CRn;
        const int j = d % CRn;
        const float4* wr = (const float4*)(w1 + (size_t)j * Cn);
        const float4* sp = (const float4*)(s + (size_t)b * Cn);
        float acc = 0.0f;
        #pragma unroll
        for (int t = 0; t < 3; ++t) {
            float4 wv = wr[lane + 64 * t];
            float4 sv = sp[lane + 64 * t];
            acc += wv.x * sv.x + wv.y * sv.y + wv.z * sv.z + wv.w * sv.w;
        }
        acc = wave_sum_bcast(acc);
        if (lane == 0) {
            float z = acc + b1[j];
            h[d] = z / (1.0f + expf(-z));       // swish
        }
    }
    grid.sync();

    // ---------- Phase 3: per row, gate then scale ----------
    for (int r = w; r < ROWS; r += NWAVE) {
        const int b = r / Cn;
        const int c = r % Cn;
        const float* hp = h  + (size_t)b * CRn;
        const float* wp = w2 + (size_t)c * CRn;
        float acc = hp[lane]        * wp[lane]
                  + hp[lane + 64]   * wp[lane + 64]
                  + hp[lane + 128]  * wp[lane + 128];
        acc = wave_sum_bcast(acc);
        const float g = 1.0f / (1.0f + expf(-(acc + b2[c])));

        const float4* xp = (const float4*)(x   + (size_t)r * HWn);
        float4*       op = (float4*)      (out + (size_t)r * HWn);
        #pragma unroll
        for (int t = 0; t < 4; ++t) {
            float4 v = xp[lane + 64 * t];
            v.x *= g; v.y *= g; v.z *= g; v.w *= g;
            op[lane + 64 * t] = v;
        }
    }
}

extern "C" void kernel_launch(void* const* d_in, const int* in_sizes, int n_in,
                              void* d_out, int out_size, void* d_ws, size_t ws_size,
                              hipStream_t stream) {
    const float* x  = (const float*)d_in[0];
    const float* w1 = (const float*)d_in[1];
    const float* b1 = (const float*)d_in[2];
    const float* w2 = (const float*)d_in[3];
    const float* b2 = (const float*)d_in[4];
    float* out = (float*)d_out;

    float* s = (float*)d_ws;            // [ROWS]    means
    float* h = s + ROWS;                // [Bn*CRn]  hidden activations

    void* args[] = { (void*)&x, (void*)&w1, (void*)&b1, (void*)&w2, (void*)&b2,
                     (void*)&out, (void*)&s, (void*)&h };
    hipLaunchCooperativeKernel((void*)se_fused, dim3(NBLK), dim3(256),
                               args, 0, stream);
}

// Round 5
// 194.383 us; speedup vs baseline: 2.0253x; 2.0253x over previous
//
#include <hip/hip_runtime.h>
#include <math.h>

#define Bn 32
#define Cn 768
#define CRn 192
#define HWn 1024   // H*W = 32*32, contiguous innermost per (b,c)

typedef float nfloat4 __attribute__((ext_vector_type(4)));  // native vec for nt store

// ---------------- Kernel 1: squeeze (mean over HW per (b,c)) ----------------
// One block per (b,c): 256 threads x float4 = 1024 floats, fully coalesced.
__global__ __launch_bounds__(256) void se_mean(const float* __restrict__ x,
                                               float* __restrict__ s) {
    const int bc = blockIdx.x;
    const float4* xp = (const float4*)(x + (size_t)bc * HWn);
    float4 v = xp[threadIdx.x];
    float sum = v.x + v.y + v.z + v.w;
    #pragma unroll
    for (int off = 32; off > 0; off >>= 1) sum += __shfl_down(sum, off);
    __shared__ float part[4];
    const int lane = threadIdx.x & 63;
    const int wid  = threadIdx.x >> 6;
    if (lane == 0) part[wid] = sum;
    __syncthreads();
    if (threadIdx.x == 0) {
        s[bc] = (part[0] + part[1] + part[2] + part[3]) * (1.0f / (float)HWn);
    }
}

// ---------------- Kernel 2: h = swish(s @ w1^T + b1) ------------------------
// One WAVE per (b,j) dot of length 768: 3 coalesced float4 loads per lane,
// then wave-reduce. 1536 blocks cover the machine; ~2 us.
__global__ __launch_bounds__(256) void se_h(const float* __restrict__ s,
                                            const float* __restrict__ w1,
                                            const float* __restrict__ b1,
                                            float* __restrict__ h) {
    const int wid  = threadIdx.x >> 6;
    const int lane = threadIdx.x & 63;
    const int b = blockIdx.x / (CRn / 4);           // 4 dots per block (one per wave)
    const int j = (blockIdx.x % (CRn / 4)) * 4 + wid;

    const float4* wr = (const float4*)(w1 + (size_t)j * Cn);   // 192 float4s
    const float4* sp = (const float4*)(s + (size_t)b * Cn);
    float acc = 0.0f;
    #pragma unroll
    for (int t = 0; t < 3; ++t) {
        float4 wv = wr[lane + 64 * t];
        float4 sv = sp[lane + 64 * t];
        acc += wv.x * sv.x + wv.y * sv.y + wv.z * sv.z + wv.w * sv.w;
    }
    #pragma unroll
    for (int off = 32; off > 0; off >>= 1) acc += __shfl_down(acc, off);
    if (lane == 0) {
        float v = acc + b1[j];
        h[b * CRn + j] = v / (1.0f + expf(-v));     // swish
    }
}

// ---------------- Kernel 3: fused gate + scale ------------------------------
// One block per (b,c). EVERY wave redundantly computes
// g = sigmoid(h[b,:] . w2[c,:] + b2[c]) via butterfly reduce (h/w2 rows are
// L1/L2-hot: 32 blocks share each w2 row, 768 share each h row). No LDS, no
// barrier -> each wave stores as soon as its own x-load + reduce retire.
__global__ __launch_bounds__(256) void se_scale_g(const float* __restrict__ x,
                                                  const float* __restrict__ h,
                                                  const float* __restrict__ w2,
                                                  const float* __restrict__ b2,
                                                  float* __restrict__ out) {
    const int bc = blockIdx.x;
    const int b = bc / Cn;
    const int c = bc % Cn;
    const int lane = threadIdx.x & 63;

    const float4* xp = (const float4*)(x + (size_t)bc * HWn);
    float4 v = xp[threadIdx.x];          // streaming load in flight first

    const float* hp = h  + (size_t)b * CRn;
    const float* wp = w2 + (size_t)c * CRn;
    float acc = hp[lane]       * wp[lane]
              + hp[lane + 64]  * wp[lane + 64]
              + hp[lane + 128] * wp[lane + 128];
    #pragma unroll
    for (int off = 32; off > 0; off >>= 1) acc += __shfl_xor(acc, off);
    const float g = 1.0f / (1.0f + expf(-(acc + b2[c])));

    nfloat4 nv = { v.x * g, v.y * g, v.z * g, v.w * g };
    nfloat4* op = (nfloat4*)(out + (size_t)bc * HWn);
    __builtin_nontemporal_store(nv, &op[threadIdx.x]);   // write-once stream
}

extern "C" void kernel_launch(void* const* d_in, const int* in_sizes, int n_in,
                              void* d_out, int out_size, void* d_ws, size_t ws_size,
                              hipStream_t stream) {
    const float* x  = (const float*)d_in[0];
    const float* w1 = (const float*)d_in[1];
    const float* b1 = (const float*)d_in[2];
    const float* w2 = (const float*)d_in[3];
    const float* b2 = (const float*)d_in[4];
    float* out = (float*)d_out;

    float* s = (float*)d_ws;            // [B*C]  means
    float* h = s + (size_t)Bn * Cn;     // [B*Cr] hidden activations

    se_mean   <<<Bn * Cn,        256, 0, stream>>>(x, s);
    se_h      <<<Bn * (CRn / 4), 256, 0, stream>>>(s, w1, b1, h);
    se_scale_g<<<Bn * Cn,        256, 0, stream>>>(x, h, w2, b2, out);
}